// Round 11
// baseline (208.646 us; speedup 1.0000x reference)
//
#include <hip/hip_runtime.h>
#include <hip/hip_bf16.h>
#include <cstdint>

typedef __attribute__((ext_vector_type(8))) short short8;
typedef __attribute__((ext_vector_type(16))) float f32x16;

// Problem constants (B, N, D, H) = (256, 100000, 512, 2048)
constexpr int M   = 256;
constexpr int NTB = 100000;
constexpr int D   = 512;
constexpr int H   = 2048;

constexpr int SR   = 32;                        // rows per strip (100000/32 = exact)
constexpr int NS   = NTB / SR;                  // 3125
constexpr float EPS_MARGIN = 6.0f;              // >> 2*eps of bf16-RNE dot error

// ---- ws layout (bytes) ----
constexpr size_t WS_CHI   = 0;                       // 256 KB  codes bf16 frag-ordered
constexpr size_t WS_CSQ   = 262144;                  // 400 KB  csq f32 per table row
constexpr size_t WS_TBF   = 671744;                  // 51.2 MB table bf16 frag-ordered
constexpr size_t WS_KEYS  = WS_TBF + (size_t)NTB * D * 2;       // [256][NS] u64 = 6.4 MB
constexpr size_t WS_IDX   = WS_KEYS + (size_t)M * NS * 8;       // 256 u32
constexpr size_t WS_H1    = WS_IDX + 1024;                      // 256*2048 f32

__device__ inline unsigned short f2bf_rne(float x) {
  unsigned u = __float_as_uint(x);
  u += 0x7fffu + ((u >> 16) & 1u);
  return (unsigned short)(u >> 16);
}
__device__ inline unsigned long long packkey(float s, unsigned n) {
  unsigned u = __float_as_uint(s);
  u = (u & 0x80000000u) ? ~u : (u | 0x80000000u);  // order-preserving
  return ((unsigned long long)u << 32) | n;
}
__device__ inline float unpackf(unsigned u) {
  u = (u & 0x80000000u) ? (u & 0x7fffffffu) : ~u;
  return __uint_as_float(u);
}
__device__ inline unsigned long long u64min(unsigned long long a, unsigned long long b) {
  return a < b ? a : b;
}

// ---------------- codes -> frag-ordered bf16 (B operand) ----------------
// element (q, k): unit = (q>>5)*2048 + (k>>4)*64 + ((k>>3)&1)*32 + (q&31), j = k&7
__global__ __launch_bounds__(256) void convert_codes_kernel(
    const float* __restrict__ codes, unsigned short* __restrict__ chi)
{
  const int i = blockIdx.x * 256 + threadIdx.x;  // 0 .. 256*512-1
  const int q = i >> 9, k = i & 511;
  const size_t unit = (size_t)(q >> 5) * 2048 + (k >> 4) * 64 + ((k >> 3) & 1) * 32 + (q & 31);
  chi[unit * 8 + (k & 7)] = f2bf_rne(codes[i]);
}

// ---------------- pass 1: table f32 -> frag-ordered bf16 + exact csq --------
// Block = one 32-row strip. Coalesced row reads, LDS-transposed to fragment
// order (XOR-swizzled banks), coalesced 32 KB write-out. Pure streaming pass.
__global__ __launch_bounds__(256) void convert_table_kernel(
    const float* __restrict__ table,
    unsigned short* __restrict__ tbf, float* __restrict__ csqg)
{
  __shared__ short8 buf[2048];     // 32 KB
  __shared__ float  csq_s[SR];

  const int t = threadIdx.x, lane = t & 63, w = t >> 6;
  const int strip = blockIdx.x, rb = strip * SR;

  #pragma unroll
  for (int i = 0; i < 8; ++i) {
    const int r = w * 8 + i;                         // local row 0..31
    const float* src = table + (size_t)(rb + r) * D + lane * 8;
    float4 v0 = *(const float4*)(src);
    float4 v1 = *(const float4*)(src + 4);
    float xs[8] = {v0.x,v0.y,v0.z,v0.w,v1.x,v1.y,v1.z,v1.w};
    short8 vh;
    float p = 0.f;
    #pragma unroll
    for (int j = 0; j < 8; ++j) { p += xs[j] * xs[j]; vh[j] = (short)f2bf_rne(xs[j]); }
    #pragma unroll
    for (int off = 1; off < 64; off <<= 1) p += __shfl_xor(p, off);
    if (lane == 0) csq_s[r] = p;
    // frag unit within strip: sg=lane>>1, half=lane&1 -> u = sg*64 + half*32 + r
    const int u = (lane >> 1) * 64 + (lane & 1) * 32 + r;
    buf[u ^ ((u >> 6) & 7)] = vh;                    // bank swizzle (involution)
  }
  __syncthreads();
  #pragma unroll
  for (int i = 0; i < 8; ++i) {
    const int u = i * 256 + t;
    ((short8*)tbf)[(size_t)strip * 2048 + u] = buf[u ^ ((u >> 6) & 7)];
  }
  if (t < SR) csqg[rb + t] = csq_s[t];
}

// ---------------- pass 2: bf16 GEMM + per-strip argmin ----------------
// Block (4 waves) = one 32-row strip; wave w = 64 queries (2 q-tiles).
// All loads are single coalesced 16B/lane in final fragment layout:
// A from tbf (1/step), B from L2-resident chi (2/step), uniform depth-4
// register queues. 2 MFMAs/step. No LDS, no barriers, acc = 32 VGPR.
__global__ __launch_bounds__(256) void dist_mfma_kernel(
    const unsigned short* __restrict__ tbf,
    const unsigned short* __restrict__ chi,
    const float* __restrict__ csqg,
    unsigned long long* __restrict__ keysT)
{
  const int t    = threadIdx.x;
  const int lane = t & 63;
  const int w    = t >> 6;        // wave -> q-tiles 2w, 2w+1
  const int half = lane >> 5;
  const int r32  = lane & 31;
  const int strip = blockIdx.x, rb = strip * SR;

  const short8* ap  = (const short8*)tbf + (size_t)strip * 2048 + lane;
  const short8* bp0 = (const short8*)chi + (size_t)(2 * w) * 2048 + lane;
  const short8* bp1 = bp0 + 2048;

  f32x16 acc0, acc1;
  #pragma unroll
  for (int r = 0; r < 16; ++r) { acc0[r] = 0.f; acc1[r] = 0.f; }

  short8 aq[4], b0q[4], b1q[4];
  #pragma unroll
  for (int p = 0; p < 4; ++p) {
    aq[p]  = ap[p * 64];
    b0q[p] = bp0[p * 64];
    b1q[p] = bp1[p * 64];
  }
  const float csqv = csqg[rb + r32];   // lane r<32 holds csq of row rb+r

  #pragma unroll
  for (int sg = 0; sg < 32; ++sg) {
    const int slot = sg & 3;
    short8 a = aq[slot], b0 = b0q[slot], b1 = b1q[slot];
    if (sg + 4 < 32) {   // uniform depth-4 refill (all 16B coalesced)
      aq[slot]  = ap[(sg + 4) * 64];
      b0q[slot] = bp0[(sg + 4) * 64];
      b1q[slot] = bp1[(sg + 4) * 64];
    }
    acc0 = __builtin_amdgcn_mfma_f32_32x32x16_bf16(a, b0, acc0, 0, 0, 0);
    acc1 = __builtin_amdgcn_mfma_f32_32x32x16_bf16(a, b1, acc1, 0, 0, 0);
  }

  // per-query argmin of score = csq - 2*dot  (x_sq const per q; sqrt monotone)
  #pragma unroll
  for (int gt = 0; gt < 2; ++gt) {
    unsigned long long best = ~0ull;
    #pragma unroll
    for (int r = 0; r < 16; ++r) {
      const int rl = (r & 3) + 8 * (r >> 2) + 4 * half;
      const float cs = __shfl(csqv, rl);
      const float dot = gt ? acc1[r] : acc0[r];
      best = u64min(best, packkey(cs - 2.f * dot, (unsigned)(rb + rl)));
    }
    best = u64min(best, __shfl_xor(best, 32));
    if (half == 0) {
      const int q = (2 * w + gt) * 32 + r32;
      keysT[(size_t)q * NS + strip] = best;
    }
  }
}

// ---------------- merge (coalesced per-q row) + flagged-strip exact rescore --
// Exactness: true-NN's strip-min <= best + 2*eps <= best + MARGIN -> flagged
// -> all 32 rows rescored in f32.
__global__ __launch_bounds__(256) void merge_rescore_kernel(
    const unsigned long long* __restrict__ keysT,
    const float* __restrict__ codes, const float* __restrict__ table,
    unsigned* __restrict__ out_idx)
{
  constexpr int FLMAX = 32;
  __shared__ unsigned long long krow[NS];
  __shared__ float xs[D];
  __shared__ unsigned long long wmin[4];
  __shared__ int flags[FLMAX];
  __shared__ int nf;
  __shared__ float rv[4];
  __shared__ int   ri[4];

  const int q = blockIdx.x, t = threadIdx.x;
  const int lane = t & 63, w = t >> 6;

  if (t == 0) nf = 0;
  for (int i = t; i < NS; i += 256) krow[i] = keysT[(size_t)q * NS + i];
  for (int d = t; d < D; d += 256) xs[d] = codes[(size_t)q * D + d];
  __syncthreads();

  unsigned long long lb = ~0ull;
  for (int i = t; i < NS; i += 256) lb = u64min(lb, krow[i]);
  #pragma unroll
  for (int off = 1; off < 64; off <<= 1) lb = u64min(lb, __shfl_xor(lb, off));
  if (lane == 0) wmin[w] = lb;
  __syncthreads();
  const unsigned long long bk =
      u64min(u64min(wmin[0], wmin[1]), u64min(wmin[2], wmin[3]));
  const float thr = unpackf((unsigned)(bk >> 32)) + EPS_MARGIN;

  for (int i = t; i < NS; i += 256) {
    if (unpackf((unsigned)(krow[i] >> 32)) <= thr) {
      int p = atomicAdd(&nf, 1);
      if (p < FLMAX) flags[p] = i;
    }
  }
  __syncthreads();
  const int nfc = min(nf, FLMAX);

  float bv = INFINITY;
  int   bi = 0x7fffffff;
  for (int f = 0; f < nfc; ++f) {
    const int sbase = flags[f] * SR;
    #pragma unroll
    for (int rr = 0; rr < 8; ++rr) {
      const int rg = sbase + w * 8 + rr;
      const float* crow = table + (size_t)rg * D + lane * 8;
      float4 c0 = *(const float4*)(crow);
      float4 c1 = *(const float4*)(crow + 4);
      float4 x0 = *(const float4*)(&xs[lane * 8]);
      float4 x1 = *(const float4*)(&xs[lane * 8 + 4]);
      float p = c0.x*c0.x - 2.f*x0.x*c0.x + c0.y*c0.y - 2.f*x0.y*c0.y
              + c0.z*c0.z - 2.f*x0.z*c0.z + c0.w*c0.w - 2.f*x0.w*c0.w
              + c1.x*c1.x - 2.f*x1.x*c1.x + c1.y*c1.y - 2.f*x1.y*c1.y
              + c1.z*c1.z - 2.f*x1.z*c1.z + c1.w*c1.w - 2.f*x1.w*c1.w;
      #pragma unroll
      for (int off = 1; off < 64; off <<= 1) p += __shfl_xor(p, off);
      if (p < bv || (p == bv && rg < bi)) { bv = p; bi = rg; }
    }
  }
  if (lane == 0) { rv[w] = bv; ri[w] = bi; }
  __syncthreads();
  if (t == 0) {
    float fv = rv[0]; int fi = ri[0];
    #pragma unroll
    for (int i = 1; i < 4; ++i)
      if (rv[i] < fv || (rv[i] == fv && ri[i] < fi)) { fv = rv[i]; fi = ri[i]; }
    out_idx[q] = (unsigned)fi;
  }
}

// ---------------- Kernel B1: h1 = relu(gather(table, idx) @ w1 + b1) --------
constexpr int BM2 = 64, BN2 = 64, BK2 = 16;

__global__ __launch_bounds__(256) void mlp1_kernel(
    const unsigned* __restrict__ final_idx,
    const float* __restrict__ table,
    const float* __restrict__ w1, const float* __restrict__ b1,
    float* __restrict__ h1)
{
  __shared__ float As[2][BK2][BM2];
  __shared__ float Bs[2][BK2][BN2];
  __shared__ unsigned idx_s[BM2];

  const int t  = threadIdx.x;
  const int tx = t & 15, ty = t >> 4;
  const int h0 = blockIdx.x * BN2;
  const int m0 = blockIdx.y * BM2;

  if (t < BM2) idx_s[t] = final_idx[m0 + t];
  __syncthreads();

  const int mr = t >> 2, c4 = (t & 3) * 4;
  const int dd = t >> 4, cb = (t & 15) * 4;
  const float* arow = table + (size_t)idx_s[mr] * D + c4;
  const float* brow = w1 + (size_t)dd * H + h0 + cb;

  float acc[4][4] = {{0.f}};

  float4 av = *(const float4*)(arow);
  float4 bv = *(const float4*)(brow);
  {
    float a[4] = {av.x, av.y, av.z, av.w};
    #pragma unroll
    for (int j = 0; j < 4; ++j) As[0][c4 + j][mr] = a[j];
    *(float4*)&Bs[0][dd][cb] = bv;
  }
  __syncthreads();

  for (int kt = 0; kt < D / BK2; ++kt) {
    const int cur = kt & 1;
    if (kt < D / BK2 - 1) {
      av = *(const float4*)(arow + (kt + 1) * BK2);
      bv = *(const float4*)(brow + (size_t)(kt + 1) * BK2 * H);
    }
    #pragma unroll
    for (int kk = 0; kk < BK2; ++kk) {
      float4 a4 = *(const float4*)&As[cur][kk][ty * 4];
      float4 b4 = *(const float4*)&Bs[cur][kk][tx * 4];
      float a[4] = {a4.x,a4.y,a4.z,a4.w}, b[4] = {b4.x,b4.y,b4.z,b4.w};
      #pragma unroll
      for (int i = 0; i < 4; ++i)
        #pragma unroll
        for (int j = 0; j < 4; ++j) acc[i][j] += a[i] * b[j];
    }
    if (kt < D / BK2 - 1) {
      float a[4] = {av.x, av.y, av.z, av.w};
      #pragma unroll
      for (int j = 0; j < 4; ++j) As[cur ^ 1][c4 + j][mr] = a[j];
      *(float4*)&Bs[cur ^ 1][dd][cb] = bv;
    }
    __syncthreads();
  }

  #pragma unroll
  for (int i = 0; i < 4; ++i) {
    const int m = m0 + ty * 4 + i;
    float v0 = acc[i][0] + b1[h0 + tx * 4 + 0];
    float v1 = acc[i][1] + b1[h0 + tx * 4 + 1];
    float v2 = acc[i][2] + b1[h0 + tx * 4 + 2];
    float v3 = acc[i][3] + b1[h0 + tx * 4 + 3];
    float4 o;
    o.x = v0 > 0.f ? v0 : 0.f;
    o.y = v1 > 0.f ? v1 : 0.f;
    o.z = v2 > 0.f ? v2 : 0.f;
    o.w = v3 > 0.f ? v3 : 0.f;
    *(float4*)(h1 + (size_t)m * H + h0 + tx * 4) = o;
  }
}

// ---------------- init d_out with biases (clears 0xAA poison) ----------
__global__ void init_out_kernel(const float* __restrict__ b2u,
                                const float* __restrict__ b2s,
                                float* __restrict__ out)
{
  const int i = blockIdx.x * blockDim.x + threadIdx.x;
  if (i < M * D) out[i] = b2u[i & (D - 1)];
  else           out[i] = b2s[i & (D - 1)];
}

// ---------------- Kernel B2: [mu|logstd] += h1 @ [w2u|w2s]  (split-K=4) ----
constexpr int KSPLIT = 4;

__global__ __launch_bounds__(256) void mlp2_kernel(
    const float* __restrict__ h1,
    const float* __restrict__ w2u, const float* __restrict__ w2s,
    float* __restrict__ out)
{
  __shared__ float As[2][BK2][BM2];
  __shared__ float Bs[2][BK2][BN2];

  const int t  = threadIdx.x;
  const int tx = t & 15, ty = t >> 4;
  const int n0 = blockIdx.x * BN2;           // over [w2u|w2s] concat (2*D wide)
  const int m0 = blockIdx.y * BM2;
  const int k0 = blockIdx.z * (H / KSPLIT);  // 512-wide K chunk

  const float* Wn = (n0 < D) ? w2u : w2s;
  const int col0 = n0 & (D - 1);

  const int mr = t >> 2, c4 = (t & 3) * 4;
  const int dd = t >> 4, cb = (t & 15) * 4;
  const float* arow = h1 + (size_t)(m0 + mr) * H + k0 + c4;
  const float* brow = Wn + (size_t)(k0 + dd) * D + col0 + cb;

  float acc[4][4] = {{0.f}};
  constexpr int NITER = (H / KSPLIT) / BK2;  // 32

  float4 av = *(const float4*)(arow);
  float4 bv = *(const float4*)(brow);
  {
    float a[4] = {av.x, av.y, av.z, av.w};
    #pragma unroll
    for (int j = 0; j < 4; ++j) As[0][c4 + j][mr] = a[j];
    *(float4*)&Bs[0][dd][cb] = bv;
  }
  __syncthreads();

  for (int kt = 0; kt < NITER; ++kt) {
    const int cur = kt & 1;
    if (kt < NITER - 1) {
      av = *(const float4*)(arow + (kt + 1) * BK2);
      bv = *(const float4*)(brow + (size_t)(kt + 1) * BK2 * D);
    }
    #pragma unroll
    for (int kk = 0; kk < BK2; ++kk) {
      float4 a4 = *(const float4*)&As[cur][kk][ty * 4];
      float4 b4 = *(const float4*)&Bs[cur][kk][tx * 4];
      float a[4] = {a4.x,a4.y,a4.z,a4.w}, b[4] = {b4.x,b4.y,b4.z,b4.w};
      #pragma unroll
      for (int i = 0; i < 4; ++i)
        #pragma unroll
        for (int j = 0; j < 4; ++j) acc[i][j] += a[i] * b[j];
    }
    if (kt < NITER - 1) {
      float a[4] = {av.x, av.y, av.z, av.w};
      #pragma unroll
      for (int j = 0; j < 4; ++j) As[cur ^ 1][c4 + j][mr] = a[j];
      *(float4*)&Bs[cur ^ 1][dd][cb] = bv;
    }
    __syncthreads();
  }

  #pragma unroll
  for (int i = 0; i < 4; ++i) {
    const int m = m0 + ty * 4 + i;
    const int c = col0 + tx * 4;
    float* dst = (n0 < D) ? (out + (size_t)m * D + c)
                          : (out + (size_t)(M * D) + (size_t)m * D + c);
    #pragma unroll
    for (int j = 0; j < 4; ++j) atomicAdd(dst + j, acc[i][j]);
  }
}

extern "C" void kernel_launch(void* const* d_in, const int* in_sizes, int n_in,
                              void* d_out, int out_size, void* d_ws, size_t ws_size,
                              hipStream_t stream)
{
  const float* codes = (const float*)d_in[0];
  const float* table = (const float*)d_in[1];
  const float* w1    = (const float*)d_in[2];
  const float* b1    = (const float*)d_in[3];
  const float* w2u   = (const float*)d_in[4];
  const float* b2u   = (const float*)d_in[5];
  const float* w2s   = (const float*)d_in[6];
  const float* b2s   = (const float*)d_in[7];
  float* out = (float*)d_out;

  unsigned short* chi  = (unsigned short*)((char*)d_ws + WS_CHI);
  float*          csqg = (float*)((char*)d_ws + WS_CSQ);
  unsigned short* tbf  = (unsigned short*)((char*)d_ws + WS_TBF);
  unsigned long long* keysT = (unsigned long long*)((char*)d_ws + WS_KEYS);
  unsigned* final_idx = (unsigned*)((char*)d_ws + WS_IDX);
  float* h1 = (float*)((char*)d_ws + WS_H1);

  convert_codes_kernel<<<(M * D) / 256, 256, 0, stream>>>(codes, chi);

  convert_table_kernel<<<NS, 256, 0, stream>>>(table, tbf, csqg);

  dist_mfma_kernel<<<NS, 256, 0, stream>>>(tbf, chi, csqg, keysT);

  merge_rescore_kernel<<<M, 256, 0, stream>>>(keysT, codes, table, final_idx);

  dim3 gB1(H / BN2, M / BM2);
  mlp1_kernel<<<gB1, 256, 0, stream>>>(final_idx, table, w1, b1, h1);

  init_out_kernel<<<(2 * M * D) / 256, 256, 0, stream>>>(b2u, b2s, out);

  dim3 gB2((2 * D) / BN2, M / BM2, KSPLIT);
  mlp2_kernel<<<gB2, 256, 0, stream>>>(h1, w2u, w2s, out);
}